// Round 4
// baseline (603.156 us; speedup 1.0000x reference)
//
#include <hip/hip_runtime.h>
#include <hip/hip_bf16.h>

// Problem constants (fixed by reference file)
#define EMBED    256
#define HEADS    8
#define LEVELS   4
#define POINTS   4
#define HEAD_DIM 32
#define BS       8
#define NQ       900
#define NV       13294          // 100*100 + 50*50 + 25*25 + 13*13
#define MV       (BS*NV)        // 106352 = 6647*16
#define MQ       (BS*NQ)        // 7200   = 450*16
#define NQOUT    384            // 256 offset cols + 128 attn cols

typedef float  f32x4  __attribute__((ext_vector_type(4)));
typedef __bf16 bf16x8 __attribute__((ext_vector_type(8)));
typedef unsigned short ushort8  __attribute__((ext_vector_type(8)));
typedef unsigned short ushort4v __attribute__((ext_vector_type(4)));

__device__ __forceinline__ unsigned short f2bf(float f) {
    unsigned u = __builtin_bit_cast(unsigned, f);
    u += 0x7FFFu + ((u >> 16) & 1u);          // RNE
    return (unsigned short)(u >> 16);
}
__device__ __forceinline__ float bf2f(unsigned short h) {
    unsigned u = ((unsigned)h) << 16;
    return __builtin_bit_cast(float, u);
}

// ---------------------------------------------------------------------------
// Prep: transpose + cast weights to bf16 (B^T layout: [n][k], k contiguous)
// ---------------------------------------------------------------------------
__global__ __launch_bounds__(256) void prep_kernel(
    const float* __restrict__ Wv,  const float* __restrict__ Woff,
    const float* __restrict__ Wattn, const float* __restrict__ Wout,
    const float* __restrict__ boff, const float* __restrict__ battn,
    unsigned short* __restrict__ WtV, unsigned short* __restrict__ WtQ,
    unsigned short* __restrict__ WtO, float* __restrict__ biasQ)
{
    int n = blockIdx.x;      // 0..383
    int k = threadIdx.x;     // 0..255
    if (n < 256) {
        WtV[n * 256 + k] = f2bf(Wv [k * 256 + n]);
        WtO[n * 256 + k] = f2bf(Wout[k * 256 + n]);
        WtQ[n * 256 + k] = f2bf(Woff[k * 256 + n]);
    } else {
        int j = n - 256;
        WtQ[n * 256 + k] = f2bf(Wattn[k * 128 + j]);
    }
    if (k == 0) biasQ[n] = (n < 256) ? boff[n] : battn[n - 256];
}

// ---------------------------------------------------------------------------
// V-projection GEMM, round-12 (R4): EXCLUSIVE-STRIP waves.
// Measured facts R0-R3: BW ~0.25 TB/s per resident wave; ANY cross-wave
// sharing of A (y-split, colset pairs, same- or cross-block) degenerates to
// full re-fetch once >1 block/CU is resident (R1: 559MB, R2: 407MB, R3:
// 463MB; all ~190us). 64KB-block pairing works (R3 occ 42%); swizzle is
// bank-neutral (identical conflict counter).
// Design: traffic is made clean BY CONSTRUCTION - each A byte read by
// exactly one wave, each C row written whole by one wave:
//   256 blocks x 1024 thr (16 waves = 4/SIMD, needs VGPR<=128).
//   Full weight matrix (256 cols x 256 k, bf16, XOR-swizzled) in 128KB LDS.
//   Each wave owns whole 16-row strips (s = base+wave, +16): loads the
//   strip fp32 (16 f32x4 back-to-back = max outstanding depth), converts
//   to bf16 (32 regs), then 8x16 MFMAs into acc[16] (all 256 out cols).
//   Epilogue adds bias (from LDS) and stores full 512B rows bf16.
// Expected: FETCH ~110MB, WRITE ~55MB, 16 waves/CU.
// ---------------------------------------------------------------------------
__global__ __launch_bounds__(1024)
void gemm_v(const float* __restrict__ A,          // [MV][256] fp32
            const unsigned short* __restrict__ Bt,// [256][256] bf16 (B^T)
            const float* __restrict__ bias,       // [256]
            unsigned short* __restrict__ C)       // [MV][256] bf16
{
    __shared__ unsigned short Ws[256 * 256];      // 128 KB
    __shared__ float Bs[256];                     // bias

    const int tid = threadIdx.x;
    #pragma unroll
    for (int i = 0; i < 8; ++i) {                 // 8192 granules / 1024 thr
        int flat = i * 1024 + tid;                // ushort8 granule index
        int row = flat >> 5, col16 = flat & 31;   // 32 granules per row
        int swz = (col16 ^ (row & 7)) * 8;        // XOR bank swizzle
        *(ushort8*)&Ws[row * 256 + swz] =
            *(const ushort8*)(Bt + (size_t)row * 256 + col16 * 8);
    }
    if (tid < 256) Bs[tid] = bias[tid];
    __syncthreads();                              // the only barrier

    const int wave = tid >> 6, lane = tid & 63;
    const int lrow = lane & 15, kq = lane >> 4;
    const int rswz = (lrow & 7) << 3;             // read-side XOR (ushorts)

    const int NS    = MV / 16;                    // 6647 strips
    const int chunk = (NS + gridDim.x - 1) / gridDim.x;
    const int base  = blockIdx.x * chunk;
    const int send  = min(NS, base + chunk);

    for (int s = base + wave; s < send; s += 16) {
        // --- load full strip: 16 rows x 256 k fp32, 16 loads in flight ---
        const float* ab = A + (size_t)(s * 16 + lrow) * 256 + kq * 8;
        f32x4 tv[16];
        #pragma unroll
        for (int c = 0; c < 8; ++c) {
            tv[2 * c]     = *(const f32x4*)(ab + c * 32);
            tv[2 * c + 1] = *(const f32x4*)(ab + c * 32 + 4);
        }
        // --- convert to bf16 (frees fp32 regs) ---
        bf16x8 av[8];
        #pragma unroll
        for (int c = 0; c < 8; ++c) {
            ushort8 vb;
            #pragma unroll
            for (int e = 0; e < 4; ++e) {
                vb[e]     = f2bf(tv[2 * c][e]);
                vb[4 + e] = f2bf(tv[2 * c + 1][e]);
            }
            av[c] = __builtin_bit_cast(bf16x8, vb);
        }
        // --- 128 MFMAs: all 256 output cols ---
        f32x4 acc[16];
        #pragma unroll
        for (int j = 0; j < 16; ++j) acc[j] = (f32x4)0.f;
        #pragma unroll
        for (int c = 0; c < 8; ++c) {
            const int wcol = (c * 32 + kq * 8) ^ rswz;
            #pragma unroll
            for (int j = 0; j < 16; ++j) {
                bf16x8 wf = *(const bf16x8*)&Ws[(j * 16 + lrow) * 256 + wcol];
                acc[j] = __builtin_amdgcn_mfma_f32_16x16x32_bf16(wf, av[c], acc[j], 0, 0, 0);
            }
        }
        // --- epilogue: bias + bf16 store, full 512B rows ---
        const size_t crow = (size_t)(s * 16 + lrow) * 256 + kq * 4;
        #pragma unroll
        for (int j = 0; j < 16; ++j) {
            f32x4 r = acc[j] + *(const f32x4*)&Bs[j * 16 + kq * 4];
            ushort4v o;
            #pragma unroll
            for (int e = 0; e < 4; ++e) o[e] = f2bf(r[e]);
            *(ushort4v*)(C + crow + j * 16) = o;
        }
    }
}

// ---------------------------------------------------------------------------
// LDS-weight streaming GEMM (K=256) for the SMALL (M=7200) GEMMs - exact R0
// configuration (padded WLDK=264, 67.6KB LDS, 512thr, no min-waves clamp).
// A is L2-resident at this size; R0 measured this portion fastest.
// ---------------------------------------------------------------------------
#define WLDK 264

template <int COLSETS, int PAR, bool OUT_BF16, bool ADD_ID>
__global__ __launch_bounds__(COLSETS * PAR * 64)
void gemm_ldsw(const float* __restrict__ A,
               const unsigned short* __restrict__ Bt,   // [Ntot][256] bf16
               const float* __restrict__ bias,          // [Ntot]
               const float* __restrict__ Ident,         // [M][Ntot] or null
               void* __restrict__ Cv, int M, int Ntot)
{
    constexpr int NC   = COLSETS * 64;     // cols per block
    constexpr int NTHR = COLSETS * PAR * 64;
    const int n0g = blockIdx.y * NC;
    __shared__ unsigned short Ws[NC * WLDK];

    const int tid = threadIdx.x;
    #pragma unroll
    for (int i = 0; i < (NC * 32) / NTHR; ++i) {        // vec8 tiles
        int flat = i * NTHR + tid;                      // ushort8 index
        int row = flat >> 5, col = (flat & 31) * 8;     // 32 vec8 per row
        *(ushort8*)&Ws[row * WLDK + col] =
            *(const ushort8*)(Bt + (size_t)(n0g + row) * 256 + col);
    }
    __syncthreads();                                    // the only barrier

    const int wave = tid >> 6, lane = tid & 63;
    const int colset = wave % COLSETS, parity = wave / COLSETS;
    const int lrow = lane & 15, kq = lane >> 4;
    const int n0 = colset * 64;

    f32x4 bj[4];
    #pragma unroll
    for (int j = 0; j < 4; ++j)
        bj[j] = *(const f32x4*)(bias + n0g + n0 + j * 16 + kq * 4);

    const int NS    = M / 16;
    const int chunk = (NS + gridDim.x - 1) / gridDim.x;
    const int send  = min(NS, blockIdx.x * chunk + chunk);
    int s = blockIdx.x * chunk + parity;
    if (s >= send) return;

    auto loadHalf = [&](f32x4 (&b)[8], int ss, int h) {
        const float* ab = A + (size_t)(ss * 16 + lrow) * 256 + h * 128 + kq * 8;
        #pragma unroll
        for (int c = 0; c < 4; ++c) {
            b[2 * c]     = *(const f32x4*)(ab + c * 32);
            b[2 * c + 1] = *(const f32x4*)(ab + c * 32 + 4);
        }
    };
    auto computeHalf = [&](f32x4 (&b)[8], int h, f32x4 (&acc)[4]) {
        #pragma unroll
        for (int c = 0; c < 4; ++c) {
            ushort8 vb;
            #pragma unroll
            for (int e = 0; e < 4; ++e) {
                vb[e]     = f2bf(b[2 * c][e]);
                vb[4 + e] = f2bf(b[2 * c + 1][e]);
            }
            bf16x8 vf = __builtin_bit_cast(bf16x8, vb);
            #pragma unroll
            for (int j = 0; j < 4; ++j) {
                bf16x8 wf = *(const bf16x8*)
                    &Ws[(n0 + j * 16 + lrow) * WLDK + h * 128 + c * 32 + kq * 8];
                acc[j] = __builtin_amdgcn_mfma_f32_16x16x32_bf16(wf, vf, acc[j], 0, 0, 0);
            }
        }
    };

    f32x4 b0[8], b1[8];
    loadHalf(b0, s, 0);
    while (true) {
        loadHalf(b1, s, 1);
        f32x4 acc[4];
        #pragma unroll
        for (int j = 0; j < 4; ++j) acc[j] = (f32x4)0.f;
        computeHalf(b0, 0, acc);            // waits only on b0
        const int sn = s + PAR;
        const bool more = sn < send;
        if (more) loadHalf(b0, sn, 0);      // in flight during computeHalf(b1)
        computeHalf(b1, 1, acc);

        const size_t crow = (size_t)(s * 16 + lrow) * Ntot + n0g + n0 + kq * 4;
        #pragma unroll
        for (int j = 0; j < 4; ++j) {
            f32x4 r = acc[j] + bj[j];
            if (ADD_ID)
                r += *(const f32x4*)(Ident + crow + j * 16);
            if (OUT_BF16) {
                ushort4v o;
                #pragma unroll
                for (int e = 0; e < 4; ++e) o[e] = f2bf(r[e]);
                *(ushort4v*)((unsigned short*)Cv + crow + j * 16) = o;
            } else {
                *(f32x4*)((float*)Cv + crow + j * 16) = r;
            }
        }
        if (!more) break;
        s = sn;
    }
}

// ---------------------------------------------------------------------------
// Sampling v2: 16 lanes per (b,q,h); lane s owns sample s. ALL corner math
// (validity, clamp, flat index, corner weights) hoisted to per-lane
// precompute; the 16-iteration broadcast loop is only 8 shuffles + 4 loads
// + 8 fma -> minimal VALU between loads, loads free to pipeline.
// ---------------------------------------------------------------------------
__device__ const int   LVL_W[4]  = {100, 50, 25, 13};
__device__ const int   LVL_H[4]  = {100, 50, 25, 13};
__device__ const int   LVL_S[4]  = {0, 10000, 12500, 13125};

__global__ __launch_bounds__(256) void sample_kernel(
    const unsigned short* __restrict__ V,   // (BS*NV, 256) bf16
    const float* __restrict__ Qout,         // (BS*NQ, 384)
    const float* __restrict__ RP,           // (BS, NQ, 4, 2)
    float* __restrict__ OutS)               // (BS*NQ, 256)
{
    const int gid = blockIdx.x * 16 + (threadIdx.x >> 4);   // triple index
    const int s   = threadIdx.x & 15;                       // lane-in-group
    const int h   = gid & 7;
    const int bq  = gid >> 3;                               // b*NQ + q
    const int b   = bq / NQ;

    const float* qrow = Qout + (size_t)bq * NQOUT;

    const int l = s >> 2;
    const float ox = qrow[h * 32 + 2 * s];
    const float oy = qrow[h * 32 + 2 * s + 1];
    float logit    = qrow[256 + h * 16 + s];
    const float rpx = RP[((size_t)bq * 4 + l) * 2 + 0];
    const float rpy = RP[((size_t)bq * 4 + l) * 2 + 1];
    const int W = LVL_W[l], H = LVL_H[l], st = LVL_S[l];
    float x = rpx * (float)W + ox - 0.5f;
    float y = rpy * (float)H + oy - 0.5f;
    float fx = floorf(x), fy = floorf(y);
    float lx = x - fx, ly = y - fy;
    int x0 = (int)fx, y0 = (int)fy;
    int x1 = x0 + 1,  y1 = y0 + 1;

    // softmax over the 16 lanes of this group
    float mx = logit;
    #pragma unroll
    for (int o = 8; o; o >>= 1) mx = fmaxf(mx, __shfl_xor(mx, o, 16));
    float e = __expf(logit - mx);
    float sum = e;
    #pragma unroll
    for (int o = 8; o; o >>= 1) sum += __shfl_xor(sum, o, 16);
    const float wgt = e / sum;

    // per-lane corner precompute (hoisted out of the broadcast loop)
    const float vx0 = (x0 >= 0 && x0 < W) ? 1.f : 0.f;
    const float vx1 = (x1 >= 0 && x1 < W) ? 1.f : 0.f;
    const float vy0 = (y0 >= 0 && y0 < H) ? 1.f : 0.f;
    const float vy1 = (y1 >= 0 && y1 < H) ? 1.f : 0.f;
    const int cx0 = min(max(x0, 0), W - 1), cx1 = min(max(x1, 0), W - 1);
    const int cy0 = min(max(y0, 0), H - 1), cy1 = min(max(y1, 0), H - 1);
    float w00 = wgt * (1.f - lx) * (1.f - ly) * vx0 * vy0;
    float w10 = wgt * lx * (1.f - ly) * vx1 * vy0;
    float w01 = wgt * (1.f - lx) * ly * vx0 * vy1;
    float w11 = wgt * lx * ly * vx1 * vy1;
    int i00 = st + cy0 * W + cx0;
    int i10 = st + cy0 * W + cx1;
    int i01 = st + cy1 * W + cx0;
    int i11 = st + cy1 * W + cx1;

    const unsigned short* vb = V + ((size_t)b * NV) * 256 + h * 32 + 2 * s;
    float ax0 = 0.f, ay0 = 0.f, ax1 = 0.f, ay1 = 0.f;

    #pragma unroll
    for (int sp = 0; sp < 16; ++sp) {
        int   j00 = __shfl(i00, sp, 16), j10 = __shfl(i10, sp, 16);
        int   j01 = __shfl(i01, sp, 16), j11 = __shfl(i11, sp, 16);
        float u00 = __shfl(w00, sp, 16), u10 = __shfl(w10, sp, 16);
        float u01 = __shfl(w01, sp, 16), u11 = __shfl(w11, sp, 16);
        unsigned p00 = *(const unsigned*)(vb + (size_t)j00 * 256);
        unsigned p10 = *(const unsigned*)(vb + (size_t)j10 * 256);
        unsigned p01 = *(const unsigned*)(vb + (size_t)j01 * 256);
        unsigned p11 = *(const unsigned*)(vb + (size_t)j11 * 256);
        ax0 = fmaf(u00, bf2f((unsigned short)(p00 & 0xFFFF)), ax0);
        ay0 = fmaf(u00, bf2f((unsigned short)(p00 >> 16)), ay0);
        ax1 = fmaf(u10, bf2f((unsigned short)(p10 & 0xFFFF)), ax1);
        ay1 = fmaf(u10, bf2f((unsigned short)(p10 >> 16)), ay1);
        ax0 = fmaf(u01, bf2f((unsigned short)(p01 & 0xFFFF)), ax0);
        ay0 = fmaf(u01, bf2f((unsigned short)(p01 >> 16)), ay0);
        ax1 = fmaf(u11, bf2f((unsigned short)(p11 & 0xFFFF)), ax1);
        ay1 = fmaf(u11, bf2f((unsigned short)(p11 >> 16)), ay1);
    }
    float2* o = (float2*)(OutS + (size_t)bq * 256 + h * 32);
    o[s] = make_float2(ax0 + ax1, ay0 + ay1);
}

// ---------------------------------------------------------------------------
extern "C" void kernel_launch(void* const* d_in, const int* in_sizes, int n_in,
                              void* d_out, int out_size, void* d_ws, size_t ws_size,
                              hipStream_t stream)
{
    const float* query  = (const float*)d_in[0];
    const float* value  = (const float*)d_in[1];
    const float* rp     = (const float*)d_in[2];
    // d_in[3] spatial_shapes: static, hardcoded
    const float* W_off  = (const float*)d_in[4];
    const float* b_off  = (const float*)d_in[5];
    const float* W_attn = (const float*)d_in[6];
    const float* b_attn = (const float*)d_in[7];
    const float* W_v    = (const float*)d_in[8];
    const float* b_v    = (const float*)d_in[9];
    const float* W_out  = (const float*)d_in[10];
    const float* b_out  = (const float*)d_in[11];

    char* ws = (char*)d_ws;
    size_t off = 0;
    unsigned short* Vbf = (unsigned short*)(ws + off); off += (size_t)MV * 256 * 2;
    float* qout         = (float*)(ws + off);          off += (size_t)MQ * NQOUT * 4;
    float* outs         = (float*)(ws + off);          off += (size_t)MQ * 256 * 4;
    unsigned short* WtV = (unsigned short*)(ws + off); off += 256 * 256 * 2;
    unsigned short* WtQ = (unsigned short*)(ws + off); off += 384 * 256 * 2;
    unsigned short* WtO = (unsigned short*)(ws + off); off += 256 * 256 * 2;
    float* biasQ        = (float*)(ws + off);          off += 384 * 4;

    prep_kernel<<<384, 256, 0, stream>>>(W_v, W_off, W_attn, W_out, b_off, b_attn,
                                         WtV, WtQ, WtO, biasQ);

    // v = value @ W_v + b_v -> bf16.  256 blocks x 1024 thr, 129KB LDS,
    // exclusive-strip waves: A read once, C rows written whole.
    gemm_v<<<256, 1024, 0, stream>>>(value, WtV, b_v, Vbf);

    // [off | attn-logits] = query @ [W_off | W_attn] + bias.  171 blocks (R0 cfg).
    gemm_ldsw<2, 4, false, false><<<dim3(57, 3), 512, 0, stream>>>(
        query, WtQ, biasQ, nullptr, qout, MQ, NQOUT);

    sample_kernel<<<(BS * NQ * HEADS) / 16, 256, 0, stream>>>(Vbf, qout, rp, outs);

    // out = out_s @ W_out + b_out + query.  114 blocks (R0 cfg).
    gemm_ldsw<2, 4, false, true><<<dim3(57, 2), 512, 0, stream>>>(
        outs, WtO, b_out, query, (float*)d_out, MQ, 256);
}

// Round 6
// 382.495 us; speedup vs baseline: 1.5769x; 1.5769x over previous
//
#include <hip/hip_runtime.h>
#include <hip/hip_bf16.h>

// Problem constants (fixed by reference file)
#define EMBED    256
#define HEADS    8
#define LEVELS   4
#define POINTS   4
#define HEAD_DIM 32
#define BS       8
#define NQ       900
#define NV       13294          // 100*100 + 50*50 + 25*25 + 13*13
#define MV       (BS*NV)        // 106352 = 6647*16
#define MQ       (BS*NQ)        // 7200   = 450*16
#define NQOUT    384            // 256 offset cols + 128 attn cols

typedef float  f32x4  __attribute__((ext_vector_type(4)));
typedef __bf16 bf16x8 __attribute__((ext_vector_type(8)));
typedef unsigned short ushort8  __attribute__((ext_vector_type(8)));
typedef unsigned short ushort4v __attribute__((ext_vector_type(4)));

__device__ __forceinline__ unsigned short f2bf(float f) {
    unsigned u = __builtin_bit_cast(unsigned, f);
    u += 0x7FFFu + ((u >> 16) & 1u);          // RNE
    return (unsigned short)(u >> 16);
}
__device__ __forceinline__ float bf2f(unsigned short h) {
    unsigned u = ((unsigned)h) << 16;
    return __builtin_bit_cast(float, u);
}

// ---------------------------------------------------------------------------
// Prep: transpose + cast weights to bf16 (B^T layout: [n][k], k contiguous)
// ---------------------------------------------------------------------------
__global__ __launch_bounds__(256) void prep_kernel(
    const float* __restrict__ Wv,  const float* __restrict__ Woff,
    const float* __restrict__ Wattn, const float* __restrict__ Wout,
    const float* __restrict__ boff, const float* __restrict__ battn,
    unsigned short* __restrict__ WtV, unsigned short* __restrict__ WtQ,
    unsigned short* __restrict__ WtO, float* __restrict__ biasQ)
{
    int n = blockIdx.x;      // 0..383
    int k = threadIdx.x;     // 0..255
    if (n < 256) {
        WtV[n * 256 + k] = f2bf(Wv [k * 256 + n]);
        WtO[n * 256 + k] = f2bf(Wout[k * 256 + n]);
        WtQ[n * 256 + k] = f2bf(Woff[k * 256 + n]);
    } else {
        int j = n - 256;
        WtQ[n * 256 + k] = f2bf(Wattn[k * 128 + j]);
    }
    if (k == 0) biasQ[n] = (n < 256) ? boff[n] : battn[n - 256];
}

// ---------------------------------------------------------------------------
// V-projection GEMM, round-13 (R5, resubmitted after infra failure):
// R0 shell + CONTIGUOUS A loads.
// Measured ladder: R0 (scattered 16-rowx64B load instrs, 8 waves/CU, clean
// traffic) = 1.95 TB/s; deep outstanding-bytes (64KB/CU) should've given far
// more -> the cap is REQUEST-pattern, not depth. R4's exclusive-strip try
// died of VGPR spill (launch_bounds(1024) -> 64 VGPR vs ~130 live).
// ONE change from R0: each load instruction is a full contiguous 1KB A row
// (64 lanes x 16B, 8 fully-consumed lines), converted to bf16 at staging and
// parked in a per-wave 8KB LDS tile (XOR granule swizzle, conflict-free b128
// reads). Wave owns strips exclusively: zero cross-wave A sharing. Inner
// loop is pure ds_read+MFMA (f2bf hoisted to staging).
// LDS: weights 128x256 bf16 swizzled (64KB) + 8 wave-tiles (64KB) = 128KB
// -> 1 block/CU, 8 waves (R0's proven-clean residency). Grid (256, 2):
// y-halves stream A twice, L3-absorbed (R0-measured FETCH=1x at this shape).
// Epilogue writes 256B line-aligned row-halves (RMW-proof).
// ---------------------------------------------------------------------------
__global__ __launch_bounds__(512)
void gemm_v(const float* __restrict__ A,            // [MV][256] fp32
            const unsigned short* __restrict__ Bt,  // [256][256] bf16 (B^T)
            const float* __restrict__ bias,         // [256]
            unsigned short* __restrict__ C)         // [MV][256] bf16
{
    __shared__ unsigned short Wsw[128 * 256];       // 64 KB, XOR-swizzled
    __shared__ unsigned short Awb[8 * 16 * 256];    // 64 KB: per-wave strip

    const int tid = threadIdx.x;
    const int n0g = blockIdx.y * 128;

    // ---- stage weights (once): rows = output cols n0g..n0g+127 ----
    #pragma unroll
    for (int i = 0; i < 8; ++i) {
        int flat = i * 512 + tid;                   // ushort8 granule id
        int row = flat >> 5, g = flat & 31;         // 32 granules per row
        int gs = g ^ (row & 7);                     // XOR bank swizzle
        *(ushort8*)&Wsw[row * 256 + gs * 8] =
            *(const ushort8*)(Bt + (size_t)(n0g + row) * 256 + g * 8);
    }
    __syncthreads();                                // the only barrier

    const int wave = tid >> 6, lane = tid & 63;
    const int lrow = lane & 15, kq = lane >> 4;
    const int swz  = lrow & 7;
    unsigned short* Aw = Awb + wave * (16 * 256);   // this wave's 8KB tile

    const int NS    = MV / 16;                      // 6647 strips
    const int chunk = (NS + gridDim.x - 1) / gridDim.x;
    const int base  = blockIdx.x * chunk;
    const int send  = min(NS, base + chunk);

    // staging lane mapping: instruction i = row i of the strip, lane covers
    // floats [lane*4, lane*4+4) -> one contiguous 1KB run per instruction.
    const int wg  = lane >> 1;                      // 16B granule 0..31
    const int whl = (lane & 1) << 2;                // ushort sub-offset 0|4

    for (int s = base + wave; s < send; s += 8) {
        // ---- stage strip: 16 contiguous 1KB loads -> bf16 -> LDS ----
        const float* gb = A + (size_t)s * 4096 + lane * 4;
        f32x4 tv[16];
        #pragma unroll
        for (int i = 0; i < 16; ++i)
            tv[i] = *(const f32x4*)(gb + i * 256);
        #pragma unroll
        for (int i = 0; i < 16; ++i) {
            ushort4v o;
            #pragma unroll
            for (int e = 0; e < 4; ++e) o[e] = f2bf(tv[i][e]);
            *(ushort4v*)&Aw[i * 256 + (((wg ^ (i & 7)) << 3) | whl)] = o;
        }

        // ---- compute: 64 MFMAs, pure LDS reads ----
        f32x4 acc[8];
        #pragma unroll
        for (int j = 0; j < 8; ++j) acc[j] = (f32x4)0.f;
        #pragma unroll
        for (int hc = 0; hc < 8; ++hc) {            // hc = h*4 + c
            const int g = hc * 4 + kq;              // k granule 0..31
            bf16x8 vf = *(const bf16x8*)&Aw[lrow * 256 + ((g ^ swz) << 3)];
            #pragma unroll
            for (int j = 0; j < 8; ++j) {
                bf16x8 wf = *(const bf16x8*)
                    &Wsw[(j * 16 + lrow) * 256 + ((g ^ swz) << 3)];
                acc[j] = __builtin_amdgcn_mfma_f32_16x16x32_bf16(wf, vf, acc[j], 0, 0, 0);
            }
        }

        // ---- epilogue: bias + bf16 store (256B line-aligned half-rows) ----
        const size_t crow = (size_t)(s * 16 + lrow) * 256 + n0g + kq * 4;
        #pragma unroll
        for (int j = 0; j < 8; ++j) {
            f32x4 r = acc[j] + *(const f32x4*)(bias + n0g + j * 16 + kq * 4);
            ushort4v o;
            #pragma unroll
            for (int e = 0; e < 4; ++e) o[e] = f2bf(r[e]);
            *(ushort4v*)(C + crow + j * 16) = o;
        }
    }
}

// ---------------------------------------------------------------------------
// LDS-weight streaming GEMM (K=256) for the SMALL (M=7200) GEMMs - exact R0
// configuration (padded WLDK=264, 67.6KB LDS, 512thr, plain launch bounds).
// A is L2-resident at this size; R0 measured this portion fastest.
// ---------------------------------------------------------------------------
#define WLDK 264

template <int COLSETS, int PAR, bool OUT_BF16, bool ADD_ID>
__global__ __launch_bounds__(COLSETS * PAR * 64)
void gemm_ldsw(const float* __restrict__ A,
               const unsigned short* __restrict__ Bt,   // [Ntot][256] bf16
               const float* __restrict__ bias,          // [Ntot]
               const float* __restrict__ Ident,         // [M][Ntot] or null
               void* __restrict__ Cv, int M, int Ntot)
{
    constexpr int NC   = COLSETS * 64;     // cols per block
    constexpr int NTHR = COLSETS * PAR * 64;
    const int n0g = blockIdx.y * NC;
    __shared__ unsigned short Ws[NC * WLDK];

    const int tid = threadIdx.x;
    #pragma unroll
    for (int i = 0; i < (NC * 32) / NTHR; ++i) {        // vec8 tiles
        int flat = i * NTHR + tid;                      // ushort8 index
        int row = flat >> 5, col = (flat & 31) * 8;     // 32 vec8 per row
        *(ushort8*)&Ws[row * WLDK + col] =
            *(const ushort8*)(Bt + (size_t)(n0g + row) * 256 + col);
    }
    __syncthreads();                                    // the only barrier

    const int wave = tid >> 6, lane = tid & 63;
    const int colset = wave % COLSETS, parity = wave / COLSETS;
    const int lrow = lane & 15, kq = lane >> 4;
    const int n0 = colset * 64;

    f32x4 bj[4];
    #pragma unroll
    for (int j = 0; j < 4; ++j)
        bj[j] = *(const f32x4*)(bias + n0g + n0 + j * 16 + kq * 4);

    const int NS    = M / 16;
    const int chunk = (NS + gridDim.x - 1) / gridDim.x;
    const int send  = min(NS, blockIdx.x * chunk + chunk);
    int s = blockIdx.x * chunk + parity;
    if (s >= send) return;

    auto loadHalf = [&](f32x4 (&b)[8], int ss, int h) {
        const float* ab = A + (size_t)(ss * 16 + lrow) * 256 + h * 128 + kq * 8;
        #pragma unroll
        for (int c = 0; c < 4; ++c) {
            b[2 * c]     = *(const f32x4*)(ab + c * 32);
            b[2 * c + 1] = *(const f32x4*)(ab + c * 32 + 4);
        }
    };
    auto computeHalf = [&](f32x4 (&b)[8], int h, f32x4 (&acc)[4]) {
        #pragma unroll
        for (int c = 0; c < 4; ++c) {
            ushort8 vb;
            #pragma unroll
            for (int e = 0; e < 4; ++e) {
                vb[e]     = f2bf(b[2 * c][e]);
                vb[4 + e] = f2bf(b[2 * c + 1][e]);
            }
            bf16x8 vf = __builtin_bit_cast(bf16x8, vb);
            #pragma unroll
            for (int j = 0; j < 4; ++j) {
                bf16x8 wf = *(const bf16x8*)
                    &Ws[(n0 + j * 16 + lrow) * WLDK + h * 128 + c * 32 + kq * 8];
                acc[j] = __builtin_amdgcn_mfma_f32_16x16x32_bf16(wf, vf, acc[j], 0, 0, 0);
            }
        }
    };

    f32x4 b0[8], b1[8];
    loadHalf(b0, s, 0);
    while (true) {
        loadHalf(b1, s, 1);
        f32x4 acc[4];
        #pragma unroll
        for (int j = 0; j < 4; ++j) acc[j] = (f32x4)0.f;
        computeHalf(b0, 0, acc);            // waits only on b0
        const int sn = s + PAR;
        const bool more = sn < send;
        if (more) loadHalf(b0, sn, 0);      // in flight during computeHalf(b1)
        computeHalf(b1, 1, acc);

        const size_t crow = (size_t)(s * 16 + lrow) * Ntot + n0g + n0 + kq * 4;
        #pragma unroll
        for (int j = 0; j < 4; ++j) {
            f32x4 r = acc[j] + bj[j];
            if (ADD_ID)
                r += *(const f32x4*)(Ident + crow + j * 16);
            if (OUT_BF16) {
                ushort4v o;
                #pragma unroll
                for (int e = 0; e < 4; ++e) o[e] = f2bf(r[e]);
                *(ushort4v*)((unsigned short*)Cv + crow + j * 16) = o;
            } else {
                *(f32x4*)((float*)Cv + crow + j * 16) = r;
            }
        }
        if (!more) break;
        s = sn;
    }
}

// ---------------------------------------------------------------------------
// Sampling v2: 16 lanes per (b,q,h); lane s owns sample s. ALL corner math
// (validity, clamp, flat index, corner weights) hoisted to per-lane
// precompute; the 16-iteration broadcast loop is only 8 shuffles + 4 loads
// + 8 fma -> minimal VALU between loads, loads free to pipeline.
// ---------------------------------------------------------------------------
__device__ const int   LVL_W[4]  = {100, 50, 25, 13};
__device__ const int   LVL_H[4]  = {100, 50, 25, 13};
__device__ const int   LVL_S[4]  = {0, 10000, 12500, 13125};

__global__ __launch_bounds__(256) void sample_kernel(
    const unsigned short* __restrict__ V,   // (BS*NV, 256) bf16
    const float* __restrict__ Qout,         // (BS*NQ, 384)
    const float* __restrict__ RP,           // (BS, NQ, 4, 2)
    float* __restrict__ OutS)               // (BS*NQ, 256)
{
    const int gid = blockIdx.x * 16 + (threadIdx.x >> 4);   // triple index
    const int s   = threadIdx.x & 15;                       // lane-in-group
    const int h   = gid & 7;
    const int bq  = gid >> 3;                               // b*NQ + q
    const int b   = bq / NQ;

    const float* qrow = Qout + (size_t)bq * NQOUT;

    const int l = s >> 2;
    const float ox = qrow[h * 32 + 2 * s];
    const float oy = qrow[h * 32 + 2 * s + 1];
    float logit    = qrow[256 + h * 16 + s];
    const float rpx = RP[((size_t)bq * 4 + l) * 2 + 0];
    const float rpy = RP[((size_t)bq * 4 + l) * 2 + 1];
    const int W = LVL_W[l], H = LVL_H[l], st = LVL_S[l];
    float x = rpx * (float)W + ox - 0.5f;
    float y = rpy * (float)H + oy - 0.5f;
    float fx = floorf(x), fy = floorf(y);
    float lx = x - fx, ly = y - fy;
    int x0 = (int)fx, y0 = (int)fy;
    int x1 = x0 + 1,  y1 = y0 + 1;

    // softmax over the 16 lanes of this group
    float mx = logit;
    #pragma unroll
    for (int o = 8; o; o >>= 1) mx = fmaxf(mx, __shfl_xor(mx, o, 16));
    float e = __expf(logit - mx);
    float sum = e;
    #pragma unroll
    for (int o = 8; o; o >>= 1) sum += __shfl_xor(sum, o, 16);
    const float wgt = e / sum;

    // per-lane corner precompute (hoisted out of the broadcast loop)
    const float vx0 = (x0 >= 0 && x0 < W) ? 1.f : 0.f;
    const float vx1 = (x1 >= 0 && x1 < W) ? 1.f : 0.f;
    const float vy0 = (y0 >= 0 && y0 < H) ? 1.f : 0.f;
    const float vy1 = (y1 >= 0 && y1 < H) ? 1.f : 0.f;
    const int cx0 = min(max(x0, 0), W - 1), cx1 = min(max(x1, 0), W - 1);
    const int cy0 = min(max(y0, 0), H - 1), cy1 = min(max(y1, 0), H - 1);
    float w00 = wgt * (1.f - lx) * (1.f - ly) * vx0 * vy0;
    float w10 = wgt * lx * (1.f - ly) * vx1 * vy0;
    float w01 = wgt * (1.f - lx) * ly * vx0 * vy1;
    float w11 = wgt * lx * ly * vx1 * vy1;
    int i00 = st + cy0 * W + cx0;
    int i10 = st + cy0 * W + cx1;
    int i01 = st + cy1 * W + cx0;
    int i11 = st + cy1 * W + cx1;

    const unsigned short* vb = V + ((size_t)b * NV) * 256 + h * 32 + 2 * s;
    float ax0 = 0.f, ay0 = 0.f, ax1 = 0.f, ay1 = 0.f;

    #pragma unroll
    for (int sp = 0; sp < 16; ++sp) {
        int   j00 = __shfl(i00, sp, 16), j10 = __shfl(i10, sp, 16);
        int   j01 = __shfl(i01, sp, 16), j11 = __shfl(i11, sp, 16);
        float u00 = __shfl(w00, sp, 16), u10 = __shfl(w10, sp, 16);
        float u01 = __shfl(w01, sp, 16), u11 = __shfl(w11, sp, 16);
        unsigned p00 = *(const unsigned*)(vb + (size_t)j00 * 256);
        unsigned p10 = *(const unsigned*)(vb + (size_t)j10 * 256);
        unsigned p01 = *(const unsigned*)(vb + (size_t)j01 * 256);
        unsigned p11 = *(const unsigned*)(vb + (size_t)j11 * 256);
        ax0 = fmaf(u00, bf2f((unsigned short)(p00 & 0xFFFF)), ax0);
        ay0 = fmaf(u00, bf2f((unsigned short)(p00 >> 16)), ay0);
        ax1 = fmaf(u10, bf2f((unsigned short)(p10 & 0xFFFF)), ax1);
        ay1 = fmaf(u10, bf2f((unsigned short)(p10 >> 16)), ay1);
        ax0 = fmaf(u01, bf2f((unsigned short)(p01 & 0xFFFF)), ax0);
        ay0 = fmaf(u01, bf2f((unsigned short)(p01 >> 16)), ay0);
        ax1 = fmaf(u11, bf2f((unsigned short)(p11 & 0xFFFF)), ax1);
        ay1 = fmaf(u11, bf2f((unsigned short)(p11 >> 16)), ay1);
    }
    float2* o = (float2*)(OutS + (size_t)bq * 256 + h * 32);
    o[s] = make_float2(ax0 + ax1, ay0 + ay1);
}

// ---------------------------------------------------------------------------
extern "C" void kernel_launch(void* const* d_in, const int* in_sizes, int n_in,
                              void* d_out, int out_size, void* d_ws, size_t ws_size,
                              hipStream_t stream)
{
    const float* query  = (const float*)d_in[0];
    const float* value  = (const float*)d_in[1];
    const float* rp     = (const float*)d_in[2];
    // d_in[3] spatial_shapes: static, hardcoded
    const float* W_off  = (const float*)d_in[4];
    const float* b_off  = (const float*)d_in[5];
    const float* W_attn = (const float*)d_in[6];
    const float* b_attn = (const float*)d_in[7];
    const float* W_v    = (const float*)d_in[8];
    const float* b_v    = (const float*)d_in[9];
    const float* W_out  = (const float*)d_in[10];
    const float* b_out  = (const float*)d_in[11];

    char* ws = (char*)d_ws;
    size_t off = 0;
    unsigned short* Vbf = (unsigned short*)(ws + off); off += (size_t)MV * 256 * 2;
    float* qout         = (float*)(ws + off);          off += (size_t)MQ * NQOUT * 4;
    float* outs         = (float*)(ws + off);          off += (size_t)MQ * 256 * 4;
    unsigned short* WtV = (unsigned short*)(ws + off); off += 256 * 256 * 2;
    unsigned short* WtQ = (unsigned short*)(ws + off); off += 384 * 256 * 2;
    unsigned short* WtO = (unsigned short*)(ws + off); off += 256 * 256 * 2;
    float* biasQ        = (float*)(ws + off);          off += 384 * 4;

    prep_kernel<<<384, 256, 0, stream>>>(W_v, W_off, W_attn, W_out, b_off, b_attn,
                                         WtV, WtQ, WtO, biasQ);

    // v = value @ W_v + b_v -> bf16.  512 blocks of 512 thr, 128KB LDS:
    // 1 block/CU, 8 waves, contiguous 1KB A-load instructions.
    gemm_v<<<dim3(256, 2), 512, 0, stream>>>(value, WtV, b_v, Vbf);

    // [off | attn-logits] = query @ [W_off | W_attn] + bias.  171 blocks (R0 cfg).
    gemm_ldsw<2, 4, false, false><<<dim3(57, 3), 512, 0, stream>>>(
        query, WtQ, biasQ, nullptr, qout, MQ, NQOUT);

    sample_kernel<<<(BS * NQ * HEADS) / 16, 256, 0, stream>>>(Vbf, qout, rp, outs);

    // out = out_s @ W_out + b_out + query.  114 blocks (R0 cfg).
    gemm_ldsw<2, 4, false, true><<<dim3(57, 2), 512, 0, stream>>>(
        outs, WtO, b_out, query, (float*)d_out, MQ, 256);
}